// Round 2
// baseline (7541.782 us; speedup 1.0000x reference)
//
#include <hip/hip_runtime.h>
#include <hip/hip_cooperative_groups.h>

namespace cg = cooperative_groups;

#define Bz 32
#define Tz 64
#define Sz 400
#define Dz 512
#define G3 1536
#define VOC 32000
#define NEGC 1e12f

typedef __attribute__((ext_vector_type(8))) short short8;
typedef __attribute__((ext_vector_type(4))) float f32x4;

__device__ __forceinline__ float sigm(float x){ return 1.f/(1.f+__expf(-x)); }
__device__ __forceinline__ float tanhfast(float x){ float e=__expf(2.f*x); return 1.f - 2.f/(e+1.f); }
__device__ __forceinline__ unsigned short f2bf(float f){
  unsigned int u = __float_as_uint(f);
  u = (u + 0x7FFFu + ((u>>16)&1u)) >> 16;
  return (unsigned short)u;
}

// ---------------- repack emb (b,t,e)->(t*B+b,e), also fill rin cols 0..511 ----
__global__ __launch_bounds__(128) void repack_emb(const float* __restrict__ emb,
    float* __restrict__ embT, float* __restrict__ rin){
  int tb = blockIdx.x; int t = tb >> 5, b = tb & 31;
  int e4 = threadIdx.x; // 128 threads * 4 floats
  float4 v = *(const float4*)&emb[((size_t)b*Tz + t)*Dz + e4*4];
  *(float4*)&embT[(size_t)tb*Dz + e4*4] = v;
  *(float4*)&rin[(size_t)tb*G3 + e4*4] = v;
}

// ---------------- generic transpose: out[e*ldo+j] = in[j*ldi+off+e] ----------
__global__ __launch_bounds__(256) void transpose_k(const float* __restrict__ in, int ldi, int off,
    float* __restrict__ out, int ldo){
  __shared__ float tile[32][33];
  int j0 = blockIdx.x*32, e0 = blockIdx.y*32;
  int tx = threadIdx.x & 31, ty = threadIdx.x >> 5; // 8 rows per pass
  for (int jj = ty; jj < 32; jj += 8)
    tile[jj][tx] = in[(size_t)(j0+jj)*ldi + off + e0 + tx];
  __syncthreads();
  for (int ee = ty; ee < 32; ee += 8)
    out[(size_t)(e0+ee)*ldo + j0 + tx] = tile[tx][ee];
}

__global__ __launch_bounds__(256) void zero_f32(float* __restrict__ p, int n){
  int i = blockIdx.x*256 + threadIdx.x;
  if (i < n) p[i] = 0.f;
}

__global__ __launch_bounds__(256) void cast_bf(const float* __restrict__ in,
    unsigned short* __restrict__ out, int n){
  for (int i = blockIdx.x*256 + threadIdx.x; i < n; i += gridDim.x*256)
    out[i] = f2bf(in[i]);
}

// ---------------- f32 tiled GEMM: C[M,N] = A[M,K] @ B[N,K]^T + bias ----------
__global__ __launch_bounds__(256) void gemm_f32(const float* __restrict__ A, int lda,
    const float* __restrict__ Bm, int ldb, const float* __restrict__ bias,
    float* __restrict__ C, int ldc, int M, int N, int K){
  __shared__ __align__(16) float As[16][68];
  __shared__ __align__(16) float Bs[16][68];
  int tid = threadIdx.x;
  int m0 = blockIdx.x * 64, n0 = blockIdx.y * 64;
  int tx = tid & 15, ty = tid >> 4;
  float acc[4][4] = {};
  int lr = tid >> 2;
  int lk = (tid & 3) << 2;
  for (int k0 = 0; k0 < K; k0 += 16){
    int m = m0 + lr;
    float4 va = (m < M) ? *(const float4*)&A[(size_t)m*lda + k0 + lk] : make_float4(0,0,0,0);
    int n = n0 + lr;
    float4 vb = (n < N) ? *(const float4*)&Bm[(size_t)n*ldb + k0 + lk] : make_float4(0,0,0,0);
    As[lk+0][lr]=va.x; As[lk+1][lr]=va.y; As[lk+2][lr]=va.z; As[lk+3][lr]=va.w;
    Bs[lk+0][lr]=vb.x; Bs[lk+1][lr]=vb.y; Bs[lk+2][lr]=vb.z; Bs[lk+3][lr]=vb.w;
    __syncthreads();
    #pragma unroll
    for (int kk = 0; kk < 16; kk++){
      float4 a = *(const float4*)&As[kk][ty*4];
      float4 b = *(const float4*)&Bs[kk][tx*4];
      float av[4] = {a.x,a.y,a.z,a.w};
      float bv[4] = {b.x,b.y,b.z,b.w};
      #pragma unroll
      for (int i = 0; i < 4; i++)
        #pragma unroll
        for (int j = 0; j < 4; j++)
          acc[i][j] += av[i]*bv[j];
    }
    __syncthreads();
  }
  #pragma unroll
  for (int i = 0; i < 4; i++){
    int m = m0 + ty*4 + i;
    if (m >= M) continue;
    #pragma unroll
    for (int j = 0; j < 4; j++){
      int n = n0 + tx*4 + j;
      if (n < N) C[(size_t)m*ldc + n] = acc[i][j] + bias[n];
    }
  }
}

// ---------------- bf16 MFMA GEMM: out = A_bf @ B_bf^T + bias ----------------
__global__ __launch_bounds__(256) void mfma_bf16(const unsigned short* __restrict__ A, int lda,
    const unsigned short* __restrict__ Bm, int ldb, const float* __restrict__ bias,
    float* __restrict__ out, int N, int K, int mode, int Vext){
  __shared__ __align__(16) unsigned short As[128][40];
  __shared__ __align__(16) unsigned short Bs[128][40];
  int tid = threadIdx.x;
  int m0 = blockIdx.x * 128, n0 = blockIdx.y * 128;
  int wid = tid >> 6, lane = tid & 63;
  int wm = (wid >> 1) * 64, wn = (wid & 1) * 64;
  f32x4 acc[4][4];
  #pragma unroll
  for (int r = 0; r < 4; r++)
    #pragma unroll
    for (int c = 0; c < 4; c++) acc[r][c] = (f32x4){0.f,0.f,0.f,0.f};
  int lr = tid >> 1;
  int lk = (tid & 1) * 16;
  int frow = lane & 15, kg = (lane >> 4) * 8;
  for (int k0 = 0; k0 < K; k0 += 32){
    *(uint4*)&As[lr][lk]     = *(const uint4*)&A[(size_t)(m0+lr)*lda + k0 + lk];
    *(uint4*)&As[lr][lk+8]   = *(const uint4*)&A[(size_t)(m0+lr)*lda + k0 + lk + 8];
    *(uint4*)&Bs[lr][lk]     = *(const uint4*)&Bm[(size_t)(n0+lr)*ldb + k0 + lk];
    *(uint4*)&Bs[lr][lk+8]   = *(const uint4*)&Bm[(size_t)(n0+lr)*ldb + k0 + lk + 8];
    __syncthreads();
    short8 af[4], bf[4];
    #pragma unroll
    for (int r = 0; r < 4; r++) af[r] = *(const short8*)&As[wm + r*16 + frow][kg];
    #pragma unroll
    for (int c = 0; c < 4; c++) bf[c] = *(const short8*)&Bs[wn + c*16 + frow][kg];
    #pragma unroll
    for (int r = 0; r < 4; r++)
      #pragma unroll
      for (int c = 0; c < 4; c++)
        acc[r][c] = __builtin_amdgcn_mfma_f32_16x16x32_bf16(af[r], bf[c], acc[r][c], 0, 0, 0);
    __syncthreads();
  }
  int crow = (lane >> 4) * 4, ccol = lane & 15;
  #pragma unroll
  for (int r = 0; r < 4; r++)
    #pragma unroll
    for (int c = 0; c < 4; c++)
      #pragma unroll
      for (int i = 0; i < 4; i++){
        int m = m0 + wm + r*16 + crow + i;
        int n = n0 + wn + c*16 + ccol;
        float v = acc[r][c][i] + bias[n];
        if (mode == 0){
          out[(size_t)m*N + n] = v;
        } else {
          int b = m & 31, t = m >> 5;
          v = (v == 0.f) ? -NEGC : v;
          out[((size_t)(b*Tz + t))*Vext + n] = v;
        }
      }
}

// ---------------- persistent cooperative phase-A kernel ----------------------
struct PA {
  const float* WT1; const float* WT2; const float* WqT;
  const float* giE; const float* b_hh;
  const float* pre; const float* mem;
  const unsigned char* mask;
  const float* v_att; const float* w_cov;
  float* hb; float* target_part; float* ctx_part; float* denom_part;
  float* p_buf; float* cov; float* energyAll; float* rin;
  float* attn_out; float* covh_out;
};

__global__ __launch_bounds__(256) void step_all(PA P){
  cg::grid_group grid = cg::this_grid();
  const int bid = blockIdx.x, tid = threadIdx.x;
  __shared__ float xc[8][513];
  __shared__ float xh[8][513];
  __shared__ float red[4][8][8][6];
  __shared__ float hnew[8][8];
  __shared__ float invd_l[8];
  __shared__ float tgt[Dz];
  __shared__ float vl[Dz], wcl[Dz];
  __shared__ float cov_l[64], p_l[64];
  __shared__ float wsum[4];
  __shared__ unsigned char mask_l[64];

  // stage A mapping
  const int bgA = bid >> 6;          // 0..3 (8 b each)
  const int kcA = bid & 63;          // 0..63 (8 k each)
  const int b3 = (tid >> 3) & 7, k3 = tid & 7, eq = tid >> 6;
  // stage B mapping
  const int bB = bid >> 3;           // 0..31
  const int scB = bid & 7;           // 0..7 (50 s each)
  const int sbase = scB * 50;
  const int wid = tid >> 6, lane = tid & 63;

  for (int i = tid; i < Dz; i += 256){ vl[i] = P.v_att[i]; wcl[i] = P.w_cov[i]; }

  for (int t = 0; t < Tz; t++){
    const int par = t & 1;
    const float* h_old = P.hb + par*Bz*Dz;
    float* h_new = P.hb + (par^1)*Bz*Dz;
    // ---- stage A: ctx normalize + GRU + target partials ----
    if (tid < 8){
      float s = 0.f;
      if (t > 0){
        for (int c = 0; c < 8; c++) s += P.denom_part[(par^1)*256 + c*32 + bgA*8 + tid];
        invd_l[tid] = 1.f/s;
      } else invd_l[tid] = 0.f;
    }
    __syncthreads();
    for (int i = tid; i < 8*Dz; i += 256){
      int bb = i >> 9, e = i & 511;
      int bg = bgA*8 + bb;
      float cv = 0.f;
      if (t > 0){
        for (int c = 0; c < 8; c++) cv += P.ctx_part[((size_t)c*32 + bg)*Dz + e];
        cv *= invd_l[bb];
        if (kcA == 0) P.rin[((size_t)(t-1)*Bz + bg)*G3 + 1024 + e] = cv;
      }
      xc[bb][e] = cv;
      xh[bb][e] = h_old[(size_t)bg*Dz + e];
    }
    __syncthreads();
    {
      float a0=0,a1=0,a2=0,a3=0,a4=0,a5=0;
      const float* w1 = P.WT1 + kcA*8 + k3;
      const float* w2 = P.WT2 + kcA*8 + k3;
      int e0 = eq*128;
      #pragma unroll 4
      for (int e = e0; e < e0+128; e++){
        float c = xc[b3][e], h = xh[b3][e];
        const float* r1 = w1 + (size_t)e*G3;
        const float* r2 = w2 + (size_t)e*G3;
        a0 += r1[0]*c;    a1 += r1[512]*c;  a2 += r1[1024]*c;
        a3 += r2[0]*h;    a4 += r2[512]*h;  a5 += r2[1024]*h;
      }
      float* rd = &red[eq][b3][k3][0];
      rd[0]=a0; rd[1]=a1; rd[2]=a2; rd[3]=a3; rd[4]=a4; rd[5]=a5;
    }
    __syncthreads();
    if (tid < 64){
      int bb = tid >> 3, kk = tid & 7;
      float s0=0,s1=0,s2=0,s3=0,s4=0,s5=0;
      #pragma unroll
      for (int q = 0; q < 4; q++){
        const float* rd = &red[q][bb][kk][0];
        s0+=rd[0]; s1+=rd[1]; s2+=rd[2]; s3+=rd[3]; s4+=rd[4]; s5+=rd[5];
      }
      int b = bgA*8 + bb, k = kcA*8 + kk;
      const float* ge = P.giE + ((size_t)t*Bz + b)*G3;
      float gir = ge[k]        + s0;
      float giz = ge[512 + k]  + s1;
      float gin = ge[1024 + k] + s2;
      float ghr = P.b_hh[k]        + s3;
      float ghz = P.b_hh[512 + k]  + s4;
      float ghn = P.b_hh[1024 + k] + s5;
      float r = sigm(gir + ghr);
      float z = sigm(giz + ghz);
      float nn = tanhfast(gin + r*ghn);
      float hv = (1.f - z)*nn + z*xh[bb][k];
      h_new[(size_t)b*Dz + k] = hv;
      P.rin[((size_t)t*Bz + b)*G3 + 512 + k] = hv;
      hnew[bb][kk] = hv;
    }
    __syncthreads();
    {
      int j = tid*2;
      const float* wq = P.WqT + (size_t)kcA*8*Dz + j;
      #pragma unroll
      for (int bb = 0; bb < 8; bb++){
        float t0=0.f, t1=0.f;
        #pragma unroll
        for (int kk = 0; kk < 8; kk++){
          float h = hnew[bb][kk];
          t0 += h*wq[(size_t)kk*Dz];
          t1 += h*wq[(size_t)kk*Dz + 1];
        }
        float* tp = P.target_part + ((size_t)kcA*32 + bgA*8 + bb)*Dz + j;
        tp[0]=t0; tp[1]=t1;
      }
    }
    grid.sync();
    // ---- stage B: tgt reduce + cov/score + energy + context partials ----
    for (int j = tid; j < Dz; j += 256){
      float s = 0.f;
      for (int c = 0; c < 64; c++) s += P.target_part[((size_t)c*32 + bB)*Dz + j];
      tgt[j] = s;
    }
    float invd = 0.f;
    if (t > 0){
      float s = 0.f;
      for (int c = 0; c < 8; c++) s += P.denom_part[(par^1)*256 + c*32 + bB];
      invd = 1.f/s;
    }
    for (int s = tid; s < 50; s += 256){
      int sg = sbase + s;
      float cv = P.cov[bB*Sz + sg];
      if (t > 0){
        float sp = P.p_buf[((size_t)(par^1)*Bz + bB)*Sz + sg] * invd;
        P.attn_out[((size_t)(t-1)*Bz + bB)*Sz + sg] = sp;
        cv += sp;
        P.cov[bB*Sz + sg] = cv;
      }
      P.covh_out[((size_t)t*Bz + bB)*Sz + sg] = cv;
      cov_l[s] = cv;
      mask_l[s] = P.mask[bB*Sz + sg];
    }
    __syncthreads();
    float dsum = 0.f;
    for (int s = wid; s < 50; s += 4){
      int sg = sbase + s;
      const float* pr = P.pre + ((size_t)bB*Sz + sg)*Dz;
      float cs = cov_l[s], acc = 0.f;
      #pragma unroll
      for (int i = 0; i < 8; i++){
        int e = lane + 64*i;
        float x = pr[e] + tgt[e] + cs*wcl[e];
        acc += vl[e]*tanhfast(x);
      }
      #pragma unroll
      for (int m = 1; m < 64; m <<= 1) acc += __shfl_xor(acc, m);
      if (lane == 0){
        float en = mask_l[s] ? -NEGC : acc;
        float p = __expf(en);
        P.energyAll[((size_t)t*Bz + bB)*Sz + sg] = en;
        P.p_buf[((size_t)par*Bz + bB)*Sz + sg] = p;
        p_l[s] = p;
        dsum += p;
      }
    }
    if (lane == 0) wsum[wid] = dsum;
    __syncthreads();
    if (tid == 0) P.denom_part[par*256 + scB*32 + bB] = wsum[0]+wsum[1]+wsum[2]+wsum[3];
    for (int e = tid; e < Dz; e += 256){
      float a = 0.f;
      const float* mrow = P.mem + ((size_t)bB*Sz + sbase)*Dz + e;
      #pragma unroll 5
      for (int s = 0; s < 50; s++) a += p_l[s]*mrow[(size_t)s*Dz];
      P.ctx_part[((size_t)scB*32 + bB)*Dz + e] = a;
    }
    grid.sync();
  }
  // ---- drain: t=63 ctx -> rin, attn row 63 ----
  if (bid < 32){
    int b = bid;
    float s = 0.f;
    for (int c = 0; c < 8; c++) s += P.denom_part[256 + c*32 + b];
    float invd = 1.f/s;
    for (int e = tid; e < Dz; e += 256){
      float cv = 0.f;
      for (int c = 0; c < 8; c++) cv += P.ctx_part[((size_t)c*32 + b)*Dz + e];
      P.rin[((size_t)63*Bz + b)*G3 + 1024 + e] = cv*invd;
    }
    for (int sg = tid; sg < Sz; sg += 256)
      P.attn_out[((size_t)63*Bz + b)*Sz + sg] = P.p_buf[((size_t)Bz + b)*Sz + sg]*invd;
  }
}

// ---------------- maxout + cast ---------------------------------------------
__global__ __launch_bounds__(256) void maxout_k(const float* __restrict__ rout,
    unsigned short* __restrict__ mo){
  int m = blockIdx.x, d = threadIdx.x;
  float a = rout[(size_t)m*Dz + 2*d], b = rout[(size_t)m*Dz + 2*d + 1];
  mo[(size_t)m*256 + d] = f2bf(fmaxf(a, b));
}

// ---------------- OOV fill ---------------------------------------------------
__global__ __launch_bounds__(64) void oov_fill(float* __restrict__ out, int Vext){
  int m = blockIdx.x;
  int b = m & 31, t = m >> 5;
  size_t base = (size_t)(b*Tz + t) * Vext;
  for (int v = VOC + threadIdx.x; v < Vext; v += 64)
    out[base + v] = -NEGC;
}

// ---------------- pointer scatter -------------------------------------------
__global__ __launch_bounds__(256) void scatter_k(const int* __restrict__ ext,
    const float* __restrict__ energyAll, float* __restrict__ out, int Vext){
  __shared__ int ex[Sz];
  __shared__ float en[Sz];
  int m = blockIdx.x;
  int t = m >> 5, b = m & 31;
  int tid = threadIdx.x;
  for (int s = tid; s < Sz; s += 256){
    ex[s] = ext[b*Sz + s];
    en[s] = energyAll[(size_t)m*Sz + s];
  }
  __syncthreads();
  size_t base = (size_t)(b*Tz + t) * Vext;
  for (int s = tid; s < Sz; s += 256){
    int v = ex[s];
    float mv = -3.4e38f; int idx = -1;
    for (int s2 = 0; s2 < Sz; s2++){
      if (ex[s2] == v && en[s2] > mv){ mv = en[s2]; idx = s2; }
    }
    if (idx == s && mv != -NEGC){
      if (v < VOC){
        float w = out[base + v] + mv;
        out[base + v] = (w == 0.f) ? -NEGC : w;
      } else {
        out[base + v] = (mv == 0.f) ? -NEGC : mv;
      }
    }
  }
}

// ============================================================================
extern "C" void kernel_launch(void* const* d_in, const int* in_sizes, int n_in,
                              void* d_out, int out_size, void* d_ws, size_t ws_size,
                              hipStream_t stream){
  const float* emb     = (const float*)d_in[0];
  const float* enc0    = (const float*)d_in[1];
  const float* mem     = (const float*)d_in[2];
  const float* W_trans = (const float*)d_in[3];
  const float* b_trans = (const float*)d_in[4];
  const float* W_ih    = (const float*)d_in[5];
  const float* W_hh    = (const float*)d_in[6];
  const float* b_ih    = (const float*)d_in[7];
  const float* b_hh    = (const float*)d_in[8];
  const float* W_pre   = (const float*)d_in[9];
  const float* b_pre   = (const float*)d_in[10];
  const float* W_q     = (const float*)d_in[11];
  const float* W_cov   = (const float*)d_in[12];
  const float* v_att   = (const float*)d_in[13];
  const float* W_ro    = (const float*)d_in[14];
  const float* b_ro    = (const float*)d_in[15];
  const float* W_logit = (const float*)d_in[16];
  const float* b_logit = (const float*)d_in[17];
  const int*   ext     = (const int*)d_in[18];
  const unsigned char* maskp = (const unsigned char*)d_in[19];
  float* out = (float*)d_out;

  const int Vext = (out_size - 2*Tz*Bz*Sz) / (Bz*Tz);

  char* ws = (char*)d_ws;
  size_t off = 0;
  auto alloc = [&](size_t bytes)->void*{
    void* p = ws + off;
    off += (bytes + 255) & ~(size_t)255;
    return p;
  };
  float* embT        = (float*)alloc((size_t)Tz*Bz*Dz*4);
  float* giE         = (float*)alloc((size_t)Tz*Bz*G3*4);
  float* preb        = (float*)alloc((size_t)Bz*Sz*Dz*4);
  float* WT1         = (float*)alloc((size_t)Dz*G3*4);
  float* WT2         = (float*)alloc((size_t)Dz*G3*4);
  float* WqT         = (float*)alloc((size_t)Dz*Dz*4);
  float* hb          = (float*)alloc((size_t)2*Bz*Dz*4);
  float* target_part = (float*)alloc((size_t)64*Bz*Dz*4);
  float* ctx_part    = (float*)alloc((size_t)8*Bz*Dz*4);
  float* denom_part  = (float*)alloc((size_t)2*256*4);
  float* p_buf       = (float*)alloc((size_t)2*Bz*Sz*4);
  float* cov         = (float*)alloc((size_t)Bz*Sz*4);
  float* energyAll   = (float*)alloc((size_t)Tz*Bz*Sz*4);
  float* rin         = (float*)alloc((size_t)Tz*Bz*G3*4);
  float* rout        = (float*)alloc((size_t)Tz*Bz*Dz*4);
  unsigned short* rin_bf = (unsigned short*)alloc((size_t)Tz*Bz*G3*2);
  unsigned short* Wro_bf = (unsigned short*)alloc((size_t)Dz*G3*2);
  unsigned short* mo_bf  = (unsigned short*)alloc((size_t)Tz*Bz*256*2);
  unsigned short* Wl_bf  = (unsigned short*)alloc((size_t)VOC*256*2);

  float* attn_out = out + (size_t)Bz*Tz*Vext;
  float* covh_out = attn_out + (size_t)Tz*Bz*Sz;

  // -------- phase 0: precompute --------
  repack_emb<<<Tz*Bz, 128, 0, stream>>>(emb, embT, rin);
  transpose_k<<<dim3(G3/32, Dz/32), 256, 0, stream>>>(W_ih, 1024, 512, WT1, G3);
  transpose_k<<<dim3(G3/32, Dz/32), 256, 0, stream>>>(W_hh, 512, 0, WT2, G3);
  transpose_k<<<dim3(Dz/32, Dz/32), 256, 0, stream>>>(W_q, 512, 0, WqT, Dz);
  zero_f32<<<(Bz*Sz + 255)/256, 256, 0, stream>>>(cov, Bz*Sz);
  gemm_f32<<<dim3(1, Dz/64), 256, 0, stream>>>(enc0, Dz, W_trans, Dz, b_trans, hb, Dz, Bz, Dz, Dz);
  gemm_f32<<<dim3(Tz*Bz/64, G3/64), 256, 0, stream>>>(embT, Dz, W_ih, 1024, b_ih, giE, G3, Tz*Bz, G3, Dz);
  gemm_f32<<<dim3(Bz*Sz/64, Dz/64), 256, 0, stream>>>(mem, Dz, W_pre, Dz, b_pre, preb, Dz, Bz*Sz, Dz, Dz);
  cast_bf<<<1024, 256, 0, stream>>>(W_ro, Wro_bf, Dz*G3);
  cast_bf<<<2048, 256, 0, stream>>>(W_logit, Wl_bf, VOC*256);

  // -------- phase A: one persistent cooperative kernel, 64 steps --------
  PA P;
  P.WT1 = WT1; P.WT2 = WT2; P.WqT = WqT; P.giE = giE; P.b_hh = b_hh;
  P.pre = preb; P.mem = mem; P.mask = maskp; P.v_att = v_att; P.w_cov = W_cov;
  P.hb = hb; P.target_part = target_part; P.ctx_part = ctx_part;
  P.denom_part = denom_part; P.p_buf = p_buf; P.cov = cov;
  P.energyAll = energyAll; P.rin = rin; P.attn_out = attn_out; P.covh_out = covh_out;
  void* kargs[] = { (void*)&P };
  hipLaunchCooperativeKernel((void*)step_all, dim3(256), dim3(256), kargs, 0, stream);

  // -------- phase B: batched readout -> maxout -> logits -> pointer --------
  cast_bf<<<2048, 256, 0, stream>>>(rin, rin_bf, Tz*Bz*G3);
  mfma_bf16<<<dim3(Tz*Bz/128, Dz/128), 256, 0, stream>>>(rin_bf, G3, Wro_bf, G3, b_ro,
                                                         rout, Dz, G3, 0, 0);
  maxout_k<<<Tz*Bz, 256, 0, stream>>>(rout, mo_bf);
  mfma_bf16<<<dim3(Tz*Bz/128, VOC/128), 256, 0, stream>>>(mo_bf, 256, Wl_bf, 256, b_logit,
                                                          out, VOC, 256, 1, Vext);
  oov_fill<<<Tz*Bz, 64, 0, stream>>>(out, Vext);
  scatter_k<<<Tz*Bz, 256, 0, stream>>>(ext, energyAll, out, Vext);
  (void)in_sizes; (void)n_in; (void)ws_size;
}

// Round 4
// 6153.565 us; speedup vs baseline: 1.2256x; 1.2256x over previous
//
#include <hip/hip_runtime.h>
#include <hip/hip_cooperative_groups.h>

namespace cg = cooperative_groups;

#define Bz 32
#define Tz 64
#define Sz 400
#define Dz 512
#define G3 1536
#define VOC 32000
#define NEGC 1e12f

typedef __attribute__((ext_vector_type(8))) short short8;
typedef __attribute__((ext_vector_type(4))) float f32x4;

__device__ __forceinline__ float sigm(float x){ return 1.f/(1.f+__expf(-x)); }
__device__ __forceinline__ float tanhfast(float x){ float e=__expf(2.f*x); return 1.f - 2.f/(e+1.f); }
__device__ __forceinline__ unsigned short f2bf(float f){
  unsigned int u = __float_as_uint(f);
  u = (u + 0x7FFFu + ((u>>16)&1u)) >> 16;
  return (unsigned short)u;
}

// ---------------- repack emb (b,t,e)->(t*B+b,e), also fill rin cols 0..511 ----
__global__ __launch_bounds__(128) void repack_emb(const float* __restrict__ emb,
    float* __restrict__ embT, float* __restrict__ rin){
  int tb = blockIdx.x; int t = tb >> 5, b = tb & 31;
  int e4 = threadIdx.x;
  float4 v = *(const float4*)&emb[((size_t)b*Tz + t)*Dz + e4*4];
  *(float4*)&embT[(size_t)tb*Dz + e4*4] = v;
  *(float4*)&rin[(size_t)tb*G3 + e4*4] = v;
}

// ---------------- generic transpose: out[e*ldo+j] = in[j*ldi+off+e] ----------
__global__ __launch_bounds__(256) void transpose_k(const float* __restrict__ in, int ldi, int off,
    float* __restrict__ out, int ldo){
  __shared__ float tile[32][33];
  int j0 = blockIdx.x*32, e0 = blockIdx.y*32;
  int tx = threadIdx.x & 31, ty = threadIdx.x >> 5;
  for (int jj = ty; jj < 32; jj += 8)
    tile[jj][tx] = in[(size_t)(j0+jj)*ldi + off + e0 + tx];
  __syncthreads();
  for (int ee = ty; ee < 32; ee += 8)
    out[(size_t)(e0+ee)*ldo + j0 + tx] = tile[tx][ee];
}

// ---------------- pack GRU weights: Wpack[kc][e][k3][8] = {ri,zi,ni,rh,zh,nh,0,0}
__global__ __launch_bounds__(256) void wpack_build(const float* __restrict__ W_ih,
    const float* __restrict__ W_hh, float* __restrict__ Wpack){
  int idx = blockIdx.x*256 + threadIdx.x;      // 64*512*8 = 262144
  int k3 = idx & 7, e = (idx>>3) & 511, kc = idx >> 12;
  int k = kc*8 + k3;
  float ri = W_ih[(size_t)k*1024 + 512 + e];
  float zi = W_ih[(size_t)(512 + k)*1024 + 512 + e];
  float ni = W_ih[(size_t)(1024 + k)*1024 + 512 + e];
  float rh = W_hh[(size_t)k*512 + e];
  float zh = W_hh[(size_t)(512 + k)*512 + e];
  float nh = W_hh[(size_t)(1024 + k)*512 + e];
  float4* o = (float4*)(Wpack + (size_t)idx*8);
  o[0] = make_float4(ri, zi, ni, rh);
  o[1] = make_float4(zh, nh, 0.f, 0.f);
}

__global__ __launch_bounds__(256) void cast_bf(const float* __restrict__ in,
    unsigned short* __restrict__ out, int n){
  for (int i = blockIdx.x*256 + threadIdx.x; i < n; i += gridDim.x*256)
    out[i] = f2bf(in[i]);
}

// ---------------- f32 tiled GEMM: C[M,N] = A[M,K] @ B[N,K]^T + bias ----------
__global__ __launch_bounds__(256) void gemm_f32(const float* __restrict__ A, int lda,
    const float* __restrict__ Bm, int ldb, const float* __restrict__ bias,
    float* __restrict__ C, int ldc, int M, int N, int K){
  __shared__ __align__(16) float As[16][68];
  __shared__ __align__(16) float Bs[16][68];
  int tid = threadIdx.x;
  int m0 = blockIdx.x * 64, n0 = blockIdx.y * 64;
  int tx = tid & 15, ty = tid >> 4;
  float acc[4][4] = {};
  int lr = tid >> 2;
  int lk = (tid & 3) << 2;
  for (int k0 = 0; k0 < K; k0 += 16){
    int m = m0 + lr;
    float4 va = (m < M) ? *(const float4*)&A[(size_t)m*lda + k0 + lk] : make_float4(0,0,0,0);
    int n = n0 + lr;
    float4 vb = (n < N) ? *(const float4*)&Bm[(size_t)n*ldb + k0 + lk] : make_float4(0,0,0,0);
    As[lk+0][lr]=va.x; As[lk+1][lr]=va.y; As[lk+2][lr]=va.z; As[lk+3][lr]=va.w;
    Bs[lk+0][lr]=vb.x; Bs[lk+1][lr]=vb.y; Bs[lk+2][lr]=vb.z; Bs[lk+3][lr]=vb.w;
    __syncthreads();
    #pragma unroll
    for (int kk = 0; kk < 16; kk++){
      float4 a = *(const float4*)&As[kk][ty*4];
      float4 b = *(const float4*)&Bs[kk][tx*4];
      float av[4] = {a.x,a.y,a.z,a.w};
      float bv[4] = {b.x,b.y,b.z,b.w};
      #pragma unroll
      for (int i = 0; i < 4; i++)
        #pragma unroll
        for (int j = 0; j < 4; j++)
          acc[i][j] += av[i]*bv[j];
    }
    __syncthreads();
  }
  #pragma unroll
  for (int i = 0; i < 4; i++){
    int m = m0 + ty*4 + i;
    if (m >= M) continue;
    #pragma unroll
    for (int j = 0; j < 4; j++){
      int n = n0 + tx*4 + j;
      if (n < N) C[(size_t)m*ldc + n] = acc[i][j] + bias[n];
    }
  }
}

// ---------------- bf16 MFMA GEMM: out = A_bf @ B_bf^T + bias ----------------
__global__ __launch_bounds__(256) void mfma_bf16(const unsigned short* __restrict__ A, int lda,
    const unsigned short* __restrict__ Bm, int ldb, const float* __restrict__ bias,
    float* __restrict__ out, int N, int K, int mode, int Vext){
  __shared__ __align__(16) unsigned short As[128][40];
  __shared__ __align__(16) unsigned short Bs[128][40];
  int tid = threadIdx.x;
  int m0 = blockIdx.x * 128, n0 = blockIdx.y * 128;
  int wid = tid >> 6, lane = tid & 63;
  int wm = (wid >> 1) * 64, wn = (wid & 1) * 64;
  f32x4 acc[4][4];
  #pragma unroll
  for (int r = 0; r < 4; r++)
    #pragma unroll
    for (int c = 0; c < 4; c++) acc[r][c] = (f32x4){0.f,0.f,0.f,0.f};
  int lr = tid >> 1;
  int lk = (tid & 1) * 16;
  int frow = lane & 15, kg = (lane >> 4) * 8;
  for (int k0 = 0; k0 < K; k0 += 32){
    *(uint4*)&As[lr][lk]     = *(const uint4*)&A[(size_t)(m0+lr)*lda + k0 + lk];
    *(uint4*)&As[lr][lk+8]   = *(const uint4*)&A[(size_t)(m0+lr)*lda + k0 + lk + 8];
    *(uint4*)&Bs[lr][lk]     = *(const uint4*)&Bm[(size_t)(n0+lr)*ldb + k0 + lk];
    *(uint4*)&Bs[lr][lk+8]   = *(const uint4*)&Bm[(size_t)(n0+lr)*ldb + k0 + lk + 8];
    __syncthreads();
    short8 af[4], bf[4];
    #pragma unroll
    for (int r = 0; r < 4; r++) af[r] = *(const short8*)&As[wm + r*16 + frow][kg];
    #pragma unroll
    for (int c = 0; c < 4; c++) bf[c] = *(const short8*)&Bs[wn + c*16 + frow][kg];
    #pragma unroll
    for (int r = 0; r < 4; r++)
      #pragma unroll
      for (int c = 0; c < 4; c++)
        acc[r][c] = __builtin_amdgcn_mfma_f32_16x16x32_bf16(af[r], bf[c], acc[r][c], 0, 0, 0);
    __syncthreads();
  }
  int crow = (lane >> 4) * 4, ccol = lane & 15;
  #pragma unroll
  for (int r = 0; r < 4; r++)
    #pragma unroll
    for (int c = 0; c < 4; c++)
      #pragma unroll
      for (int i = 0; i < 4; i++){
        int m = m0 + wm + r*16 + crow + i;
        int n = n0 + wn + c*16 + ccol;
        float v = acc[r][c][i] + bias[n];
        if (mode == 0){
          out[(size_t)m*N + n] = v;
        } else {
          int b = m & 31, t = m >> 5;
          v = (v == 0.f) ? -NEGC : v;
          out[((size_t)(b*Tz + t))*Vext + n] = v;
        }
      }
}

// ---------------- persistent cooperative phase-A kernel ----------------------
struct PA {
  const float* Wpack; const float* WqT;
  const float* giE; const float* b_hh;
  const float* pre; const float* mem;
  const unsigned char* mask;
  const float* v_att; const float* w_cov;
  float* hb; float* target_part; float* ctx_part; float* denom_part;
  float* energyAll; float* rin;
  float* attn_out; float* covh_out;
};

struct SA { float xc[8][516]; float xh[8][516]; float red[8][8][8][6]; float hnew[8][8]; float invd[8]; };
struct SB { float tgtp[4][512]; float ctxw[8][512]; float wsum[8]; };

// 256 blocks x 512 threads: 1 block/CU guaranteed co-resident (proven envelope)
__global__ __launch_bounds__(512, 2) void step_all(PA P){
  cg::grid_group grid = cg::this_grid();
  const int bid = blockIdx.x, tid = threadIdx.x;
  __shared__ __align__(16) char smem[sizeof(SA) > sizeof(SB) ? sizeof(SA) : sizeof(SB)];
  SA& A = *reinterpret_cast<SA*>(smem);
  SB& Bs = *reinterpret_cast<SB*>(smem);

  // stage A identity: 4 bgroups x 64 k-chunks
  const int bgA = bid >> 6;
  const int kcA = bid & 63;
  const int eqA = tid >> 6, b3 = (tid >> 3) & 7, k3 = tid & 7;
  // stage B identity: 32 b x 8 s-chunks (50 s each)
  const int bB = bid >> 3;
  const int scB = bid & 7;
  const int sbase = scB * 50;
  const int wvid = tid >> 6, lane = tid & 63;

  // persistent per-lane (lane 0 of each wave) stage-B state: s = wvid + 8*i, i<7
  float p_reg[7] = {0,0,0,0,0,0,0};
  float cov_reg[7] = {0,0,0,0,0,0,0};
  int   mask_reg[7] = {0,0,0,0,0,0,0};
  if (lane == 0){
    #pragma unroll
    for (int i = 0; i < 7; i++){
      int s = wvid + 8*i;
      if (s < 50) mask_reg[i] = P.mask[bB*Sz + sbase + s];
    }
  }
  // per-lane constant attention vectors (8 elems each)
  f32x4 vva = *(const f32x4*)(P.v_att + lane*8);
  f32x4 vvb = *(const f32x4*)(P.v_att + lane*8 + 4);
  f32x4 wva = *(const f32x4*)(P.w_cov + lane*8);
  f32x4 wvb = *(const f32x4*)(P.w_cov + lane*8 + 4);

  for (int t = 0; t < Tz; t++){
    const int par = t & 1;
    // ================= stage A: ctx normalize + GRU + target partials ========
    {
      const float* h_old = P.hb + par*Bz*Dz;
      float* h_new = P.hb + (par^1)*Bz*Dz;
      if (tid < 8){
        float s = 0.f;
        if (t > 0){
          for (int c = 0; c < 8; c++) s += P.denom_part[(par^1)*256 + c*32 + bgA*8 + tid];
          A.invd[tid] = 1.f/s;
        } else A.invd[tid] = 0.f;
      }
      __syncthreads();
      for (int i = tid; i < 1024; i += 512){
        int bb = i >> 7, e4 = (i & 127) << 2;
        int b = bgA*8 + bb;
        f32x4 cv = (f32x4){0.f,0.f,0.f,0.f};
        if (t > 0){
          #pragma unroll
          for (int c = 0; c < 8; c++)
            cv += *(const f32x4*)&P.ctx_part[(((size_t)c*32 + b) << 9) + e4];
          cv *= A.invd[bb];
          if (kcA == 0) *(f32x4*)&P.rin[((size_t)(t-1)*Bz + b)*G3 + 1024 + e4] = cv;
        }
        *(f32x4*)&A.xc[bb][e4] = cv;
        *(f32x4*)&A.xh[bb][e4] = *(const f32x4*)&h_old[((size_t)b << 9) + e4];
      }
      __syncthreads();
      {
        float a0=0,a1=0,a2=0,a3=0,a4=0,a5=0;
        int e0 = eqA*64;
        const f32x4* wp = (const f32x4*)P.Wpack + (((size_t)kcA*512 + e0)*8 + k3)*2;
        #pragma unroll 4
        for (int ee = 0; ee < 64; ee++){
          f32x4 wa = wp[0], wb = wp[1];
          float c = A.xc[b3][e0+ee], h = A.xh[b3][e0+ee];
          a0 += wa[0]*c; a1 += wa[1]*c; a2 += wa[2]*c;
          a3 += wa[3]*h; a4 += wb[0]*h; a5 += wb[1]*h;
          wp += 16;
        }
        float* rd = &A.red[eqA][b3][k3][0];
        rd[0]=a0; rd[1]=a1; rd[2]=a2; rd[3]=a3; rd[4]=a4; rd[5]=a5;
      }
      __syncthreads();
      if (tid < 64){
        int bb = tid >> 3, kk = tid & 7;
        float s0=0,s1=0,s2=0,s3=0,s4=0,s5=0;
        #pragma unroll
        for (int q = 0; q < 8; q++){
          const float* rd = &A.red[q][bb][kk][0];
          s0+=rd[0]; s1+=rd[1]; s2+=rd[2]; s3+=rd[3]; s4+=rd[4]; s5+=rd[5];
        }
        int b = bgA*8 + bb, k = kcA*8 + kk;
        const float* ge = P.giE + ((size_t)t*Bz + b)*G3;
        float gir = ge[k]        + s0;
        float giz = ge[512 + k]  + s1;
        float gin = ge[1024 + k] + s2;
        float ghr = P.b_hh[k]        + s3;
        float ghz = P.b_hh[512 + k]  + s4;
        float ghn = P.b_hh[1024 + k] + s5;
        float r = sigm(gir + ghr);
        float z = sigm(giz + ghz);
        float nn = tanhfast(gin + r*ghn);
        float hv = (1.f - z)*nn + z*A.xh[bb][k];
        h_new[((size_t)b << 9) + k] = hv;
        P.rin[((size_t)t*Bz + b)*G3 + 512 + k] = hv;
        A.hnew[bb][kk] = hv;
      }
      __syncthreads();
      {
        int j = tid;
        float w[8];
        #pragma unroll
        for (int kk = 0; kk < 8; kk++)
          w[kk] = P.WqT[(size_t)(kcA*8 + kk)*Dz + j];
        #pragma unroll
        for (int bb = 0; bb < 8; bb++){
          float s = 0.f;
          #pragma unroll
          for (int kk = 0; kk < 8; kk++) s += A.hnew[bb][kk]*w[kk];
          P.target_part[(((size_t)kcA*32 + bgA*8 + bb) << 9) + j] = s;
        }
      }
    }
    grid.sync();
    // ================= stage B: tgt reduce + cov/energy + context ============
    {
      int cq = tid >> 7, jj = (tid & 127) << 2;
      f32x4 sacc = (f32x4){0.f,0.f,0.f,0.f};
      #pragma unroll 4
      for (int c = 0; c < 16; c++)
        sacc += *(const f32x4*)&P.target_part[(((size_t)(cq*16 + c)*32 + bB) << 9) + jj];
      *(f32x4*)&Bs.tgtp[cq][jj] = sacc;
      float invd = 0.f;
      if (t > 0){
        float s = 0.f;
        for (int c = 0; c < 8; c++) s += P.denom_part[(par^1)*256 + c*32 + bB];
        invd = 1.f/s;
      }
      __syncthreads();
      f32x4 ta = (f32x4){0.f,0.f,0.f,0.f}, tb = ta;
      #pragma unroll
      for (int q = 0; q < 4; q++){
        ta += *(const f32x4*)&Bs.tgtp[q][lane*8];
        tb += *(const f32x4*)&Bs.tgtp[q][lane*8 + 4];
      }
      f32x4 ca = (f32x4){0.f,0.f,0.f,0.f}, cb = ca;
      float dsum = 0.f;
      #pragma unroll
      for (int i = 0; i < 7; i++){
        int s = wvid + 8*i;
        if (s < 50){
          int sg = sbase + s;
          float cv = 0.f; int mk = 0;
          if (lane == 0){
            cv = cov_reg[i]; mk = mask_reg[i];
            if (t > 0){
              float sp = p_reg[i]*invd;
              P.attn_out[((size_t)(t-1)*Bz + bB)*Sz + sg] = sp;
              cv += sp; cov_reg[i] = cv;
            }
            P.covh_out[((size_t)t*Bz + bB)*Sz + sg] = cv;
          }
          cv = __shfl(cv, 0); mk = __shfl(mk, 0);
          const f32x4* pr = (const f32x4*)(P.pre + (((size_t)bB*Sz + sg) << 9)) + lane*2;
          f32x4 pa = pr[0], pb = pr[1];
          float acc;
          acc  = vva[0]*tanhfast(pa[0] + ta[0] + cv*wva[0]);
          acc += vva[1]*tanhfast(pa[1] + ta[1] + cv*wva[1]);
          acc += vva[2]*tanhfast(pa[2] + ta[2] + cv*wva[2]);
          acc += vva[3]*tanhfast(pa[3] + ta[3] + cv*wva[3]);
          acc += vvb[0]*tanhfast(pb[0] + tb[0] + cv*wvb[0]);
          acc += vvb[1]*tanhfast(pb[1] + tb[1] + cv*wvb[1]);
          acc += vvb[2]*tanhfast(pb[2] + tb[2] + cv*wvb[2]);
          acc += vvb[3]*tanhfast(pb[3] + tb[3] + cv*wvb[3]);
          #pragma unroll
          for (int m = 1; m < 64; m <<= 1) acc += __shfl_xor(acc, m);
          float en = mk ? -NEGC : acc;
          float p = __expf(en);
          if (lane == 0){
            P.energyAll[((size_t)t*Bz + bB)*Sz + sg] = en;
            p_reg[i] = p; dsum += p;
          }
          const f32x4* mr = (const f32x4*)(P.mem + (((size_t)bB*Sz + sg) << 9)) + lane*2;
          f32x4 ma = mr[0], mb = mr[1];
          ca += p*ma; cb += p*mb;
        }
      }
      if (lane == 0) Bs.wsum[wvid] = dsum;
      *(f32x4*)&Bs.ctxw[wvid][lane*8] = ca;
      *(f32x4*)&Bs.ctxw[wvid][lane*8 + 4] = cb;
      __syncthreads();
      if (tid == 0){
        float s = 0.f;
        #pragma unroll
        for (int w = 0; w < 8; w++) s += Bs.wsum[w];
        P.denom_part[par*256 + scB*32 + bB] = s;
      }
      {
        float s = 0.f;
        #pragma unroll
        for (int w = 0; w < 8; w++) s += Bs.ctxw[w][tid];
        P.ctx_part[(((size_t)scB*32 + bB) << 9) + tid] = s;
      }
    }
    grid.sync();
  }
  // ================= drain: t=63 score + ctx ================================
  {
    float invdf = 0.f;
    for (int c = 0; c < 8; c++) invdf += P.denom_part[256 + c*32 + bB];
    invdf = 1.f/invdf;
    if (lane == 0){
      #pragma unroll
      for (int i = 0; i < 7; i++){
        int s = wvid + 8*i;
        if (s < 50)
          P.attn_out[((size_t)63*Bz + bB)*Sz + sbase + s] = p_reg[i]*invdf;
      }
    }
  }
  if (bid < 32){
    int b2 = bid;
    float inv2 = 0.f;
    for (int c = 0; c < 8; c++) inv2 += P.denom_part[256 + c*32 + b2];
    inv2 = 1.f/inv2;
    float cvv = 0.f;
    for (int c = 0; c < 8; c++) cvv += P.ctx_part[(((size_t)c*32 + b2) << 9) + tid];
    P.rin[((size_t)63*Bz + b2)*G3 + 1024 + tid] = cvv*inv2;
  }
}

// ---------------- maxout + cast ---------------------------------------------
__global__ __launch_bounds__(256) void maxout_k(const float* __restrict__ rout,
    unsigned short* __restrict__ mo){
  int m = blockIdx.x, d = threadIdx.x;
  float a = rout[(size_t)m*Dz + 2*d], b = rout[(size_t)m*Dz + 2*d + 1];
  mo[(size_t)m*256 + d] = f2bf(fmaxf(a, b));
}

// ---------------- OOV fill ---------------------------------------------------
__global__ __launch_bounds__(64) void oov_fill(float* __restrict__ out, int Vext){
  int m = blockIdx.x;
  int b = m & 31, t = m >> 5;
  size_t base = (size_t)(b*Tz + t) * Vext;
  for (int v = VOC + threadIdx.x; v < Vext; v += 64)
    out[base + v] = -NEGC;
}

// ---------------- pointer scatter -------------------------------------------
__global__ __launch_bounds__(256) void scatter_k(const int* __restrict__ ext,
    const float* __restrict__ energyAll, float* __restrict__ out, int Vext){
  __shared__ int ex[Sz];
  __shared__ float en[Sz];
  int m = blockIdx.x;
  int t = m >> 5, b = m & 31;
  int tid = threadIdx.x;
  for (int s = tid; s < Sz; s += 256){
    ex[s] = ext[b*Sz + s];
    en[s] = energyAll[(size_t)m*Sz + s];
  }
  __syncthreads();
  size_t base = (size_t)(b*Tz + t) * Vext;
  for (int s = tid; s < Sz; s += 256){
    int v = ex[s];
    float mv = -3.4e38f; int idx = -1;
    for (int s2 = 0; s2 < Sz; s2++){
      if (ex[s2] == v && en[s2] > mv){ mv = en[s2]; idx = s2; }
    }
    if (idx == s && mv != -NEGC){
      if (v < VOC){
        float w = out[base + v] + mv;
        out[base + v] = (w == 0.f) ? -NEGC : w;
      } else {
        out[base + v] = (mv == 0.f) ? -NEGC : mv;
      }
    }
  }
}

// ============================================================================
extern "C" void kernel_launch(void* const* d_in, const int* in_sizes, int n_in,
                              void* d_out, int out_size, void* d_ws, size_t ws_size,
                              hipStream_t stream){
  const float* emb     = (const float*)d_in[0];
  const float* enc0    = (const float*)d_in[1];
  const float* mem     = (const float*)d_in[2];
  const float* W_trans = (const float*)d_in[3];
  const float* b_trans = (const float*)d_in[4];
  const float* W_ih    = (const float*)d_in[5];
  const float* W_hh    = (const float*)d_in[6];
  const float* b_ih    = (const float*)d_in[7];
  const float* b_hh    = (const float*)d_in[8];
  const float* W_pre   = (const float*)d_in[9];
  const float* b_pre   = (const float*)d_in[10];
  const float* W_q     = (const float*)d_in[11];
  const float* W_cov   = (const float*)d_in[12];
  const float* v_att   = (const float*)d_in[13];
  const float* W_ro    = (const float*)d_in[14];
  const float* b_ro    = (const float*)d_in[15];
  const float* W_logit = (const float*)d_in[16];
  const float* b_logit = (const float*)d_in[17];
  const int*   ext     = (const int*)d_in[18];
  const unsigned char* maskp = (const unsigned char*)d_in[19];
  float* out = (float*)d_out;

  const int Vext = (out_size - 2*Tz*Bz*Sz) / (Bz*Tz);

  char* ws = (char*)d_ws;
  size_t off = 0;
  auto alloc = [&](size_t bytes)->void*{
    void* p = ws + off;
    off += (bytes + 255) & ~(size_t)255;
    return p;
  };
  float* embT        = (float*)alloc((size_t)Tz*Bz*Dz*4);
  float* giE         = (float*)alloc((size_t)Tz*Bz*G3*4);
  float* preb        = (float*)alloc((size_t)Bz*Sz*Dz*4);
  float* Wpack       = (float*)alloc((size_t)64*512*8*8*4);
  float* WqT         = (float*)alloc((size_t)Dz*Dz*4);
  float* hb          = (float*)alloc((size_t)2*Bz*Dz*4);
  float* target_part = (float*)alloc((size_t)64*Bz*Dz*4);
  float* ctx_part    = (float*)alloc((size_t)8*Bz*Dz*4);
  float* denom_part  = (float*)alloc((size_t)2*256*4);
  float* energyAll   = (float*)alloc((size_t)Tz*Bz*Sz*4);
  float* rin         = (float*)alloc((size_t)Tz*Bz*G3*4);
  float* rout        = (float*)alloc((size_t)Tz*Bz*Dz*4);
  unsigned short* rin_bf = (unsigned short*)alloc((size_t)Tz*Bz*G3*2);
  unsigned short* Wro_bf = (unsigned short*)alloc((size_t)Dz*G3*2);
  unsigned short* mo_bf  = (unsigned short*)alloc((size_t)Tz*Bz*256*2);
  unsigned short* Wl_bf  = (unsigned short*)alloc((size_t)VOC*256*2);

  float* attn_out = out + (size_t)Bz*Tz*Vext;
  float* covh_out = attn_out + (size_t)Tz*Bz*Sz;

  // -------- phase 0: precompute --------
  repack_emb<<<Tz*Bz, 128, 0, stream>>>(emb, embT, rin);
  wpack_build<<<1024, 256, 0, stream>>>(W_ih, W_hh, Wpack);
  transpose_k<<<dim3(Dz/32, Dz/32), 256, 0, stream>>>(W_q, 512, 0, WqT, Dz);
  gemm_f32<<<dim3(1, Dz/64), 256, 0, stream>>>(enc0, Dz, W_trans, Dz, b_trans, hb, Dz, Bz, Dz, Dz);
  gemm_f32<<<dim3(Tz*Bz/64, G3/64), 256, 0, stream>>>(embT, Dz, W_ih, 1024, b_ih, giE, G3, Tz*Bz, G3, Dz);
  gemm_f32<<<dim3(Bz*Sz/64, Dz/64), 256, 0, stream>>>(mem, Dz, W_pre, Dz, b_pre, preb, Dz, Bz*Sz, Dz, Dz);
  cast_bf<<<1024, 256, 0, stream>>>(W_ro, Wro_bf, Dz*G3);
  cast_bf<<<2048, 256, 0, stream>>>(W_logit, Wl_bf, VOC*256);

  // -------- phase A: one persistent cooperative kernel, 64 steps --------
  PA P;
  P.Wpack = Wpack; P.WqT = WqT; P.giE = giE; P.b_hh = b_hh;
  P.pre = preb; P.mem = mem; P.mask = maskp; P.v_att = v_att; P.w_cov = W_cov;
  P.hb = hb; P.target_part = target_part; P.ctx_part = ctx_part;
  P.denom_part = denom_part;
  P.energyAll = energyAll; P.rin = rin; P.attn_out = attn_out; P.covh_out = covh_out;
  void* kargs[] = { (void*)&P };
  hipLaunchCooperativeKernel((void*)step_all, dim3(256), dim3(512), kargs, 0, stream);

  // -------- phase B: batched readout -> maxout -> logits -> pointer --------
  cast_bf<<<2048, 256, 0, stream>>>(rin, rin_bf, Tz*Bz*G3);
  mfma_bf16<<<dim3(Tz*Bz/128, Dz/128), 256, 0, stream>>>(rin_bf, G3, Wro_bf, G3, b_ro,
                                                         rout, Dz, G3, 0, 0);
  maxout_k<<<Tz*Bz, 256, 0, stream>>>(rout, mo_bf);
  mfma_bf16<<<dim3(Tz*Bz/128, VOC/128), 256, 0, stream>>>(mo_bf, 256, Wl_bf, 256, b_logit,
                                                          out, VOC, 256, 1, Vext);
  oov_fill<<<Tz*Bz, 64, 0, stream>>>(out, Vext);
  scatter_k<<<Tz*Bz, 256, 0, stream>>>(ext, energyAll, out, Vext);
  (void)in_sizes; (void)n_in; (void)ws_size;
}